// Round 1
// baseline (202.746 us; speedup 1.0000x reference)
//
#include <hip/hip_runtime.h>

#define NWS 16
#define ZD 512
#define MD 10
#define MM 100   // MD*MD

// ---------------- Kernel A: lie_alg[b,w,i,j] = sum_z z[b,w,z]*basis[w,z,i,j]
// grid (16, 4096/TILE_B), block 256
#define TILE_B 128
#define BK 32

__global__ __launch_bounds__(256) void einsum_kernel(const float* __restrict__ z,
                                                     const float* __restrict__ basis,
                                                     float* __restrict__ out) {
    __shared__ float Zst[BK][TILE_B + 4];   // transposed: [kk][row]
    __shared__ float Bs[BK][112];           // cols 100..111 are dummy (never stored)

    const int w   = blockIdx.x;
    const int b0  = blockIdx.y * TILE_B;
    const int tid = threadIdx.x;
    const int rg  = tid >> 2;        // 0..63
    const int cg  = tid & 3;         // 0..3
    const int r0  = rg * 2;
    const int c0  = cg * 28;

    float acc[2][28];
    #pragma unroll
    for (int r = 0; r < 2; ++r)
        #pragma unroll
        for (int c = 0; c < 28; ++c) acc[r][c] = 0.f;

    for (int k0 = 0; k0 < ZD; k0 += BK) {
        __syncthreads();
        // ---- stage z tile (transposed) : 128 rows x 32 k
        #pragma unroll
        for (int i = 0; i < 4; ++i) {
            int idx = tid + i * 256;              // 0..1023
            int row = idx >> 3;
            int k4  = idx & 7;
            const float4 v = *reinterpret_cast<const float4*>(
                z + (size_t)(b0 + row) * (NWS * ZD) + (size_t)w * ZD + k0 + k4 * 4);
            Zst[k4 * 4 + 0][row] = v.x;
            Zst[k4 * 4 + 1][row] = v.y;
            Zst[k4 * 4 + 2][row] = v.z;
            Zst[k4 * 4 + 3][row] = v.w;
        }
        // ---- stage basis tile : 32 k x 100 ij
        #pragma unroll
        for (int i = 0; i < 4; ++i) {
            int idx = tid + i * 256;              // need < 800
            if (idx < BK * 25) {
                int kk = idx / 25;
                int q  = idx - kk * 25;
                const float4 v = *reinterpret_cast<const float4*>(
                    basis + (size_t)w * (ZD * MM) + (size_t)(k0 + kk) * MM + q * 4);
                *reinterpret_cast<float4*>(&Bs[kk][q * 4]) = v;
            }
        }
        __syncthreads();

        #pragma unroll 4
        for (int kk = 0; kk < BK; ++kk) {
            float bv[28];
            #pragma unroll
            for (int q = 0; q < 7; ++q) {
                const float4 v = *reinterpret_cast<const float4*>(&Bs[kk][c0 + q * 4]);
                bv[q * 4 + 0] = v.x; bv[q * 4 + 1] = v.y;
                bv[q * 4 + 2] = v.z; bv[q * 4 + 3] = v.w;
            }
            const float2 zv = *reinterpret_cast<const float2*>(&Zst[kk][r0]);
            #pragma unroll
            for (int c = 0; c < 28; ++c) {
                acc[0][c] = fmaf(zv.x, bv[c], acc[0][c]);
                acc[1][c] = fmaf(zv.y, bv[c], acc[1][c]);
            }
        }
    }

    // ---- store lie_alg (fp32) into d_out; cg==3 owns cols 84..99 only
    #pragma unroll
    for (int r = 0; r < 2; ++r) {
        float* dst = out + ((size_t)(b0 + r0 + r) * NWS + w) * MM + c0;
        const int nq = (cg == 3) ? 4 : 7;
        for (int q = 0; q < nq; ++q) {
            float4 v = make_float4(acc[r][q * 4 + 0], acc[r][q * 4 + 1],
                                   acc[r][q * 4 + 2], acc[r][q * 4 + 3]);
            *reinterpret_cast<float4*>(dst + q * 4) = v;
        }
    }
}

// ---------------- Kernel B: in-place expm of 10x10 matrices in d_out
// 32 matrices/block, 10 threads per matrix (one row each), block 320
#define NMAT 32
#define NTERMS 12

__global__ __launch_bounds__(320) void expm_kernel(float* __restrict__ out) {
    __shared__ float P[NMAT][MD][12];      // padded rows (12 floats)
    const int t = threadIdx.x;
    const int m = t / 10;
    const int i = t - m * 10;
    float* mat = out + ((size_t)blockIdx.x * NMAT + m) * MM;

    // A row i -> registers (read BEFORE any write; each thread owns its row)
    float a[MD];
    #pragma unroll
    for (int q = 0; q < 5; ++q) {
        float2 v = *reinterpret_cast<const float2*>(mat + i * MD + q * 2);
        a[q * 2] = v.x; a[q * 2 + 1] = v.y;
    }

    // Horner: p = I + A/N ; for k=N-1..1 : p = I + (A*p)/k
    float p[MD];
    #pragma unroll
    for (int j = 0; j < MD; ++j)
        p[j] = a[j] * (1.f / NTERMS) + ((i == j) ? 1.f : 0.f);

    #pragma unroll
    for (int k = NTERMS - 1; k >= 1; --k) {
        __syncthreads();
        #pragma unroll
        for (int j = 0; j < MD; ++j) P[m][i][j] = p[j];
        __syncthreads();
        float nr[MD];
        #pragma unroll
        for (int j = 0; j < MD; ++j) nr[j] = 0.f;
        #pragma unroll
        for (int kk = 0; kk < MD; ++kk) {
            const float av = a[kk];
            #pragma unroll
            for (int j = 0; j < MD; ++j)
                nr[j] = fmaf(av, P[m][kk][j], nr[j]);
        }
        const float invk = 1.f / (float)k;
        #pragma unroll
        for (int j = 0; j < MD; ++j)
            p[j] = nr[j] * invk + ((i == j) ? 1.f : 0.f);
    }

    #pragma unroll
    for (int q = 0; q < 5; ++q) {
        float2 v = make_float2(p[q * 2], p[q * 2 + 1]);
        *reinterpret_cast<float2*>(mat + i * MD + q * 2) = v;
    }
}

extern "C" void kernel_launch(void* const* d_in, const int* in_sizes, int n_in,
                              void* d_out, int out_size, void* d_ws, size_t ws_size,
                              hipStream_t stream) {
    const float* z     = (const float*)d_in[0];   // [4096,16,512]
    const float* basis = (const float*)d_in[1];   // [16,512,10,10]
    float* out = (float*)d_out;                   // [4096,16,10,10]

    dim3 gridA(NWS, 4096 / TILE_B);
    einsum_kernel<<<gridA, 256, 0, stream>>>(z, basis, out);

    const int nmat_total = 4096 * NWS;            // 65536
    expm_kernel<<<nmat_total / NMAT, 320, 0, stream>>>(out);
}

// Round 2
// 118.729 us; speedup vs baseline: 1.7076x; 1.7076x over previous
//
#include <hip/hip_runtime.h>

#define NWS 16
#define ZD 512
#define MD 10
#define MM 100
#define NPAD 112

typedef __attribute__((ext_vector_type(8))) short bf16x8;
typedef __attribute__((ext_vector_type(4))) float f32x4;

static __device__ __forceinline__ short f2bf(float x) {
    unsigned u = __float_as_uint(x);
    unsigned r = u + 0x7FFFu + ((u >> 16) & 1u);   // round-to-nearest-even
    return (short)(r >> 16);
}

// ---------------- Kernel 0: basis fp32 [w][k][ij] -> bf16 transposed Bt [w][ij(pad112)][k]
__global__ __launch_bounds__(256) void prep_basis(const float* __restrict__ basis,
                                                  unsigned short* __restrict__ Bt) {
    int idx = blockIdx.x * 256 + threadIdx.x;      // 16*112*512 total
    int k    = idx & (ZD - 1);
    int rest = idx >> 9;                           // w*112 + col
    int col  = rest % NPAD;
    int w    = rest / NPAD;
    float v = 0.f;
    if (col < MM) v = basis[((size_t)w * ZD + k) * MM + col];
    Bt[idx] = (unsigned short)f2bf(v);
}

// ---------------- Kernel A: lie_alg = z @ basis via bf16 MFMA, no LDS, no barriers
// grid (16, 4096/64), block 256 (4 waves). Wave v owns rows mb*64+v*16 .. +15, all 112 cols.
__global__ __launch_bounds__(256) void einsum_mfma(const float* __restrict__ z,
                                                   const unsigned short* __restrict__ Bt,
                                                   float* __restrict__ out) {
    const int w    = blockIdx.x;
    const int mb   = blockIdx.y;
    const int tid  = threadIdx.x;
    const int wave = tid >> 6;
    const int lane = tid & 63;
    const int l15  = lane & 15;
    const int k8   = lane >> 4;          // 0..3

    const int brow = mb * 64 + wave * 16 + l15;
    const float* zp = z + (size_t)brow * (NWS * ZD) + (size_t)w * ZD + k8 * 8;
    const unsigned short* bp = Bt + ((size_t)w * NPAD + l15) * ZD + k8 * 8;

    f32x4 acc[7];
    #pragma unroll
    for (int i = 0; i < 7; ++i) acc[i] = (f32x4){0.f, 0.f, 0.f, 0.f};

    #pragma unroll 4
    for (int k0 = 0; k0 < ZD; k0 += 32) {
        // A fragment: 8 fp32 -> bf16x8 (row = l15, k = k8*8 + t)
        const float4 a0 = *reinterpret_cast<const float4*>(zp + k0);
        const float4 a1 = *reinterpret_cast<const float4*>(zp + k0 + 4);
        bf16x8 af;
        af[0] = f2bf(a0.x); af[1] = f2bf(a0.y); af[2] = f2bf(a0.z); af[3] = f2bf(a0.w);
        af[4] = f2bf(a1.x); af[5] = f2bf(a1.y); af[6] = f2bf(a1.z); af[7] = f2bf(a1.w);

        #pragma unroll
        for (int nf = 0; nf < 7; ++nf) {
            // B fragment: col = nf*16 + l15, k = k8*8 + t  (Bt is [col][k] bf16)
            const bf16x8 bf = *reinterpret_cast<const bf16x8*>(bp + (size_t)nf * 16 * ZD + k0);
            acc[nf] = __builtin_amdgcn_mfma_f32_16x16x32_bf16(af, bf, acc[nf], 0, 0, 0);
        }
    }

    // C layout: col = lane&15, row = (lane>>4)*4 + r
    const int rowbase = mb * 64 + wave * 16 + k8 * 4;
    #pragma unroll
    for (int nf = 0; nf < 7; ++nf) {
        const int col = nf * 16 + l15;
        if (col < MM) {
            #pragma unroll
            for (int r = 0; r < 4; ++r) {
                out[((size_t)(rowbase + r) * NWS + w) * MM + col] = acc[nf][r];
            }
        }
    }
}

// ---------------- Kernel B: in-place expm of 10x10 matrices in d_out
#define NMAT 32
#define NTERMS 12

__global__ __launch_bounds__(320) void expm_kernel(float* __restrict__ out) {
    __shared__ float P[NMAT][MD][12];
    const int t = threadIdx.x;
    const int m = t / 10;
    const int i = t - m * 10;
    float* mat = out + ((size_t)blockIdx.x * NMAT + m) * MM;

    float a[MD];
    #pragma unroll
    for (int q = 0; q < 5; ++q) {
        float2 v = *reinterpret_cast<const float2*>(mat + i * MD + q * 2);
        a[q * 2] = v.x; a[q * 2 + 1] = v.y;
    }

    float p[MD];
    #pragma unroll
    for (int j = 0; j < MD; ++j)
        p[j] = a[j] * (1.f / NTERMS) + ((i == j) ? 1.f : 0.f);

    #pragma unroll
    for (int k = NTERMS - 1; k >= 1; --k) {
        __syncthreads();
        #pragma unroll
        for (int j = 0; j < MD; ++j) P[m][i][j] = p[j];
        __syncthreads();
        float nr[MD];
        #pragma unroll
        for (int j = 0; j < MD; ++j) nr[j] = 0.f;
        #pragma unroll
        for (int kk = 0; kk < MD; ++kk) {
            const float av = a[kk];
            #pragma unroll
            for (int j = 0; j < MD; ++j)
                nr[j] = fmaf(av, P[m][kk][j], nr[j]);
        }
        const float invk = 1.f / (float)k;
        #pragma unroll
        for (int j = 0; j < MD; ++j)
            p[j] = nr[j] * invk + ((i == j) ? 1.f : 0.f);
    }

    #pragma unroll
    for (int q = 0; q < 5; ++q) {
        float2 v = make_float2(p[q * 2], p[q * 2 + 1]);
        *reinterpret_cast<float2*>(mat + i * MD + q * 2) = v;
    }
}

extern "C" void kernel_launch(void* const* d_in, const int* in_sizes, int n_in,
                              void* d_out, int out_size, void* d_ws, size_t ws_size,
                              hipStream_t stream) {
    const float* z     = (const float*)d_in[0];   // [4096,16,512]
    const float* basis = (const float*)d_in[1];   // [16,512,10,10]
    float* out = (float*)d_out;                   // [4096,16,10,10]
    unsigned short* Bt = (unsigned short*)d_ws;   // [16][112][512] bf16 = 1.8 MB

    const int bt_elems = NWS * NPAD * ZD;         // 917504
    prep_basis<<<bt_elems / 256, 256, 0, stream>>>(basis, Bt);

    dim3 gridA(NWS, 4096 / 64);
    einsum_mfma<<<gridA, 256, 0, stream>>>(z, Bt, out);

    const int nmat_total = 4096 * NWS;            // 65536
    expm_kernel<<<nmat_total / NMAT, 320, 0, stream>>>(out);
}

// Round 3
// 112.519 us; speedup vs baseline: 1.8019x; 1.0552x over previous
//
#include <hip/hip_runtime.h>
#include <hip/hip_bf16.h>

#define NWS 16
#define ZD 512
#define MD 10
#define MM 100
#define NPAD 112

typedef __attribute__((ext_vector_type(8))) short bf16x8;
typedef __attribute__((ext_vector_type(4))) float f32x4;

static __device__ __forceinline__ unsigned short f2bf(float x) {
    union { __hip_bfloat16 h; unsigned short u; } cv;
    cv.h = __float2bfloat16(x);
    return cv.u;
}

// ---------------- Kernel 0: basis fp32 [w][k][ij] -> bf16 transposed Bt [w][ij(pad112)][k]
__global__ __launch_bounds__(256) void prep_basis(const float* __restrict__ basis,
                                                  unsigned short* __restrict__ Bt) {
    int idx = blockIdx.x * 256 + threadIdx.x;      // 16*112*512 total
    int k    = idx & (ZD - 1);
    int rest = idx >> 9;                           // w*112 + col
    int col  = rest % NPAD;
    int w    = rest / NPAD;
    float v = 0.f;
    if (col < MM) v = basis[((size_t)w * ZD + k) * MM + col];
    Bt[idx] = f2bf(v);
}

// ---------------- Kernel A: lie_alg = z @ basis via bf16 MFMA
// grid (16, 32), block 256 (4 waves). Wave: 2 M-frags (32 rows) x 7 N-frags (112 cols).
// 3-stage register pipeline (prefetch distance 2 K-steps).
__global__ __launch_bounds__(256, 2) void einsum_mfma(const float* __restrict__ z,
                                                      const unsigned short* __restrict__ Bt,
                                                      float* __restrict__ out) {
    const int w    = blockIdx.x;
    const int mb   = blockIdx.y;          // 0..31
    const int wave = threadIdx.x >> 6;
    const int lane = threadIdx.x & 63;
    const int l15  = lane & 15;
    const int k8   = lane >> 4;           // 0..3

    const int rowA = mb * 128 + wave * 32 + l15;            // M-frag 0; frag 1 at +16
    const float* zp0 = z + (size_t)rowA * (NWS * ZD) + (size_t)w * ZD + k8 * 8;
    const float* zp1 = zp0 + (size_t)16 * (NWS * ZD);
    const unsigned short* bp = Bt + ((size_t)w * NPAD + l15) * ZD + k8 * 8;

    f32x4 acc[2][7];
    #pragma unroll
    for (int m = 0; m < 2; ++m)
        #pragma unroll
        for (int n = 0; n < 7; ++n) acc[m][n] = (f32x4){0.f, 0.f, 0.f, 0.f};

    float4 a[3][2][2];     // [stage][mfrag][half]
    bf16x8 b[3][7];        // [stage][nfrag]

    auto LOAD = [&](int s, int k0) {
        a[s][0][0] = *reinterpret_cast<const float4*>(zp0 + k0);
        a[s][0][1] = *reinterpret_cast<const float4*>(zp0 + k0 + 4);
        a[s][1][0] = *reinterpret_cast<const float4*>(zp1 + k0);
        a[s][1][1] = *reinterpret_cast<const float4*>(zp1 + k0 + 4);
        #pragma unroll
        for (int nf = 0; nf < 7; ++nf)
            b[s][nf] = *reinterpret_cast<const bf16x8*>(bp + (size_t)nf * 16 * ZD + k0);
    };

    LOAD(0, 0);
    LOAD(1, 32);

    #pragma unroll
    for (int it = 0; it < 16; ++it) {
        const int s = it % 3;
        // convert A fragments of stage s
        bf16x8 af[2];
        #pragma unroll
        for (int m = 0; m < 2; ++m) {
            af[m][0] = (short)f2bf(a[s][m][0].x);
            af[m][1] = (short)f2bf(a[s][m][0].y);
            af[m][2] = (short)f2bf(a[s][m][0].z);
            af[m][3] = (short)f2bf(a[s][m][0].w);
            af[m][4] = (short)f2bf(a[s][m][1].x);
            af[m][5] = (short)f2bf(a[s][m][1].y);
            af[m][6] = (short)f2bf(a[s][m][1].z);
            af[m][7] = (short)f2bf(a[s][m][1].w);
        }
        #pragma unroll
        for (int nf = 0; nf < 7; ++nf) {
            acc[0][nf] = __builtin_amdgcn_mfma_f32_16x16x32_bf16(af[0], b[s][nf], acc[0][nf], 0, 0, 0);
            acc[1][nf] = __builtin_amdgcn_mfma_f32_16x16x32_bf16(af[1], b[s][nf], acc[1][nf], 0, 0, 0);
        }
        if (it + 2 < 16) LOAD((it + 2) % 3, (it + 2) * 32);
    }

    // C layout: col = lane&15, row = (lane>>4)*4 + r
    #pragma unroll
    for (int m = 0; m < 2; ++m) {
        const int rowbase = mb * 128 + wave * 32 + m * 16 + k8 * 4;
        #pragma unroll
        for (int nf = 0; nf < 7; ++nf) {
            const int col = nf * 16 + l15;
            if (col < MM) {
                #pragma unroll
                for (int r = 0; r < 4; ++r)
                    out[((size_t)(rowbase + r) * NWS + w) * MM + col] = acc[m][nf][r];
            }
        }
    }
}

// ---------------- Kernel B: in-place expm of 10x10 matrices
// block 320 = 64 matrices x 5 threads; each thread owns 2 columns, full A in registers.
#define EXP_NT 8

__global__ __launch_bounds__(320) void expm_kernel(float* __restrict__ out) {
    __shared__ float As[64 * 100];
    const int t = threadIdx.x;
    const size_t base = (size_t)blockIdx.x * (64 * 100);

    // stage 64 matrices (6400 floats) into LDS, float4-coalesced, linear layout
    #pragma unroll
    for (int q = 0; q < 5; ++q) {
        const int idx = (q * 320 + t) * 4;
        *reinterpret_cast<float4*>(&As[idx]) =
            *reinterpret_cast<const float4*>(out + base + idx);
    }
    __syncthreads();

    const int m  = t / 5;
    const int c  = t - m * 5;
    const int j0 = 2 * c, j1 = 2 * c + 1;
    const float* A = &As[m * 100];

    // full matrix into registers (static indexing only)
    float a[100];
    #pragma unroll
    for (int q = 0; q < 25; ++q) {
        const float4 v = *reinterpret_cast<const float4*>(A + q * 4);
        a[q * 4 + 0] = v.x; a[q * 4 + 1] = v.y;
        a[q * 4 + 2] = v.z; a[q * 4 + 3] = v.w;
    }

    // Horner: P = I + A/N; for k=N-1..1: P = I + (A*P)/k   (columns j0, j1)
    float p0[10], p1[10];
    #pragma unroll
    for (int i = 0; i < 10; ++i) {
        p0[i] = a[i * 10 + j0] * (1.f / EXP_NT) + ((i == j0) ? 1.f : 0.f);
        p1[i] = a[i * 10 + j1] * (1.f / EXP_NT) + ((i == j1) ? 1.f : 0.f);
    }

    #pragma unroll
    for (int k = EXP_NT - 1; k >= 1; --k) {
        float n0[10], n1[10];
        #pragma unroll
        for (int i = 0; i < 10; ++i) { n0[i] = 0.f; n1[i] = 0.f; }
        #pragma unroll
        for (int kk = 0; kk < 10; ++kk) {
            const float q0 = p0[kk], q1 = p1[kk];
            #pragma unroll
            for (int i = 0; i < 10; ++i) {
                n0[i] = fmaf(a[i * 10 + kk], q0, n0[i]);
                n1[i] = fmaf(a[i * 10 + kk], q1, n1[i]);
            }
        }
        const float invk = 1.f / (float)k;
        #pragma unroll
        for (int i = 0; i < 10; ++i) {
            p0[i] = n0[i] * invk + ((i == j0) ? 1.f : 0.f);
            p1[i] = n1[i] * invk + ((i == j1) ? 1.f : 0.f);
        }
    }

    // store columns j0, j1 (adjacent -> float2)
    #pragma unroll
    for (int i = 0; i < 10; ++i) {
        *reinterpret_cast<float2*>(out + base + m * 100 + i * 10 + j0) =
            make_float2(p0[i], p1[i]);
    }
}

extern "C" void kernel_launch(void* const* d_in, const int* in_sizes, int n_in,
                              void* d_out, int out_size, void* d_ws, size_t ws_size,
                              hipStream_t stream) {
    const float* z     = (const float*)d_in[0];   // [4096,16,512]
    const float* basis = (const float*)d_in[1];   // [16,512,10,10]
    float* out = (float*)d_out;                   // [4096,16,10,10]
    unsigned short* Bt = (unsigned short*)d_ws;   // [16][112][512] bf16 = 1.8 MB

    const int bt_elems = NWS * NPAD * ZD;         // 917504
    prep_basis<<<bt_elems / 256, 256, 0, stream>>>(basis, Bt);

    dim3 gridA(NWS, 32);
    einsum_mfma<<<gridA, 256, 0, stream>>>(z, Bt, out);

    const int nmat_total = 4096 * NWS;            // 65536
    expm_kernel<<<nmat_total / 64, 320, 0, stream>>>(out);
}

// Round 4
// 56.279 us; speedup vs baseline: 3.6025x; 1.9993x over previous
//
#include <hip/hip_runtime.h>
#include <hip/hip_bf16.h>

#define NWS 16
#define ZD 512
#define MM 100
#define NCOL 112             // padded col count (7 x 16)
#define HALF_BYTES 57344     // 112 cols * 256 k * 2 B
#define PANEL_BYTES 114688   // 112 cols * 512 k * 2 B

typedef __attribute__((ext_vector_type(8))) short bf16x8;
typedef __attribute__((ext_vector_type(4))) float f32x4;

static __device__ __forceinline__ unsigned short f2bf(float x) {
    union { __hip_bfloat16 h; unsigned short u; } cv;
    cv.h = __float2bfloat16(x);
    return cv.u;
}

// ---------------- Kernel 0: basis fp32 [w][k][ij] -> bf16 swizzled panel
// Bt[w][half][col][k] with byte swizzle ((col&7)<<4) XOR'd into the k-offset,
// so a linear LDS copy yields conflict-free ds_read_b128 fragments.
__global__ __launch_bounds__(256) void prep_basis(const float* __restrict__ basis,
                                                  unsigned char* __restrict__ Bt) {
    const int idx = blockIdx.x * 256 + threadIdx.x;   // 16*64*112 = 114688
    const int col  = idx % NCOL;
    const int rest = idx / NCOL;
    const int g    = rest & 63;        // k-group of 8
    const int w    = rest >> 6;

    bf16x8 pk;
    #pragma unroll
    for (int e = 0; e < 8; ++e) {
        const int k = g * 8 + e;
        const float v = (col < MM) ? basis[((size_t)(w * ZD + k)) * MM + col] : 0.f;
        pk[e] = (short)f2bf(v);
    }
    const int half = g >> 5;
    const int gl   = g & 31;
    const size_t off = (size_t)w * PANEL_BYTES + (size_t)half * HALF_BYTES
                     + (size_t)col * 512 + (size_t)((gl * 16) ^ ((col & 7) << 4));
    *reinterpret_cast<bf16x8*>(Bt + off) = pk;
}

// ---------------- Kernel A: lie_alg = z @ basis via bf16 MFMA, B panel in LDS
// grid (16, 32), block 512 (8 waves, 16 rows each = 128 rows/block)
__global__ __launch_bounds__(512, 4) void einsum_mfma(const float* __restrict__ z,
                                                      const unsigned char* __restrict__ Btg,
                                                      float* __restrict__ out) {
    __shared__ __align__(16) unsigned char Bs[HALF_BYTES];
    const int w     = blockIdx.x;
    const int chunk = blockIdx.y;
    const int tid   = threadIdx.x;
    const int wave  = tid >> 6;
    const int lane  = tid & 63;
    const int l15   = lane & 15;
    const int k8    = lane >> 4;

    const int row = chunk * 128 + wave * 16 + l15;
    const float* zp = z + (size_t)row * (NWS * ZD) + (size_t)w * ZD + k8 * 8;
    const unsigned char* bt = Btg + (size_t)w * PANEL_BYTES;

    int bbase[7];
    #pragma unroll
    for (int nf = 0; nf < 7; ++nf) bbase[nf] = (nf * 16 + l15) * 512;
    const int bswz = (l15 & 7) << 4;

    f32x4 acc[7];
    #pragma unroll
    for (int nf = 0; nf < 7; ++nf) acc[nf] = (f32x4){0.f, 0.f, 0.f, 0.f};

    float4 za[2][2];                       // [buf][half-of-8]; buf = step&1 (static)
    za[0][0] = *reinterpret_cast<const float4*>(zp);
    za[0][1] = *reinterpret_cast<const float4*>(zp + 4);

    #pragma unroll
    for (int half = 0; half < 2; ++half) {
        if (half) __syncthreads();         // all waves done reading previous panel
        // stage half-panel (linear 57344-byte copy, layout incl. swizzle is global)
        float4 st[7];
        const float4* gsrc = reinterpret_cast<const float4*>(bt + half * HALF_BYTES);
        #pragma unroll
        for (int i = 0; i < 7; ++i) st[i] = gsrc[i * 512 + tid];
        #pragma unroll
        for (int i = 0; i < 7; ++i)
            *reinterpret_cast<float4*>(Bs + i * 8192 + tid * 16) = st[i];
        __syncthreads();

        #pragma unroll
        for (int step = 0; step < 8; ++step) {
            const int gs  = half * 8 + step;
            const int cur = step & 1;      // compile-time (loops unrolled)
            const int nxt = cur ^ 1;
            if (gs < 15) {                 // prefetch next K-step of z
                za[nxt][0] = *reinterpret_cast<const float4*>(zp + (gs + 1) * 32);
                za[nxt][1] = *reinterpret_cast<const float4*>(zp + (gs + 1) * 32 + 4);
            }
            bf16x8 af;
            af[0] = (short)f2bf(za[cur][0].x);
            af[1] = (short)f2bf(za[cur][0].y);
            af[2] = (short)f2bf(za[cur][0].z);
            af[3] = (short)f2bf(za[cur][0].w);
            af[4] = (short)f2bf(za[cur][1].x);
            af[5] = (short)f2bf(za[cur][1].y);
            af[6] = (short)f2bf(za[cur][1].z);
            af[7] = (short)f2bf(za[cur][1].w);

            const int klb = (step * 64 + k8 * 16) ^ bswz;
            #pragma unroll
            for (int nf = 0; nf < 7; ++nf) {
                const bf16x8 bfr = *reinterpret_cast<const bf16x8*>(Bs + bbase[nf] + klb);
                acc[nf] = __builtin_amdgcn_mfma_f32_16x16x32_bf16(af, bfr, acc[nf], 0, 0, 0);
            }
        }
    }

    // C layout: col = lane&15, row = (lane>>4)*4 + r  (verified R2/R3)
    const int rowbase = chunk * 128 + wave * 16 + k8 * 4;
    #pragma unroll
    for (int nf = 0; nf < 7; ++nf) {
        const int col = nf * 16 + l15;
        if (col < MM) {
            #pragma unroll
            for (int r = 0; r < 4; ++r)
                out[((size_t)(rowbase + r) * NWS + w) * MM + col] = acc[nf][r];
        }
    }
}

// ---------------- Kernel B: in-place expm of 10x10 matrices
// block 320 = 64 matrices x 5 threads; thread owns 2 columns; A in registers
// (STATIC indexing only — init columns read from LDS to avoid scratch demotion).
#define EXP_NT 6

__global__ __launch_bounds__(320, 2) void expm_kernel(float* __restrict__ out) {
    __shared__ float As[64 * 100];
    const int t = threadIdx.x;
    const size_t base = (size_t)blockIdx.x * 6400;

    #pragma unroll
    for (int q = 0; q < 5; ++q) {
        const int idx = (q * 320 + t) * 4;
        *reinterpret_cast<float4*>(&As[idx]) =
            *reinterpret_cast<const float4*>(out + base + idx);
    }
    __syncthreads();

    const int m  = t / 5;
    const int c  = t - m * 5;
    const int j0 = 2 * c, j1 = j0 + 1;
    const float* A = &As[m * 100];

    float a[100];                          // statically indexed ONLY -> registers
    #pragma unroll
    for (int q = 0; q < 25; ++q) {
        const float4 v = *reinterpret_cast<const float4*>(A + q * 4);
        a[q * 4 + 0] = v.x; a[q * 4 + 1] = v.y;
        a[q * 4 + 2] = v.z; a[q * 4 + 3] = v.w;
    }

    // init: P = I + A/N — columns j0,j1 read from LDS (runtime index OK there)
    float p0[10], p1[10];
    #pragma unroll
    for (int i = 0; i < 10; ++i) {
        p0[i] = A[i * 10 + j0] * (1.f / EXP_NT) + ((i == j0) ? 1.f : 0.f);
        p1[i] = A[i * 10 + j1] * (1.f / EXP_NT) + ((i == j1) ? 1.f : 0.f);
    }

    #pragma unroll
    for (int k = EXP_NT - 1; k >= 1; --k) {
        float n0[10], n1[10];
        #pragma unroll
        for (int i = 0; i < 10; ++i) { n0[i] = 0.f; n1[i] = 0.f; }
        #pragma unroll
        for (int kk = 0; kk < 10; ++kk) {
            const float q0 = p0[kk], q1 = p1[kk];
            #pragma unroll
            for (int i = 0; i < 10; ++i) {
                n0[i] = fmaf(a[i * 10 + kk], q0, n0[i]);
                n1[i] = fmaf(a[i * 10 + kk], q1, n1[i]);
            }
        }
        const float invk = 1.f / (float)k;
        #pragma unroll
        for (int i = 0; i < 10; ++i) {
            p0[i] = n0[i] * invk + ((i == j0) ? 1.f : 0.f);
            p1[i] = n1[i] * invk + ((i == j1) ? 1.f : 0.f);
        }
    }

    #pragma unroll
    for (int i = 0; i < 10; ++i)
        *reinterpret_cast<float2*>(out + base + m * 100 + i * 10 + j0) =
            make_float2(p0[i], p1[i]);
}

extern "C" void kernel_launch(void* const* d_in, const int* in_sizes, int n_in,
                              void* d_out, int out_size, void* d_ws, size_t ws_size,
                              hipStream_t stream) {
    const float* z     = (const float*)d_in[0];   // [4096,16,512]
    const float* basis = (const float*)d_in[1];   // [16,512,10,10]
    float* out = (float*)d_out;                   // [4096,16,10,10]
    unsigned char* Bt = (unsigned char*)d_ws;     // 16 * 114688 B = 1.83 MB

    prep_basis<<<(NWS * 64 * NCOL) / 256, 256, 0, stream>>>(basis, Bt);

    dim3 gridA(NWS, 32);
    einsum_mfma<<<gridA, 512, 0, stream>>>(z, Bt, out);

    expm_kernel<<<(4096 * NWS) / 64, 320, 0, stream>>>(out);
}